// Round 1
// baseline (4843.292 us; speedup 1.0000x reference)
//
#include <hip/hip_runtime.h>
#include <cmath>

#define SLOPE 0.2f
#define EPSV 1e-5f
#define ORD_NEG_INF 0x007FFFFFu

__device__ __forceinline__ unsigned f2ord(float f) {
    unsigned b = __float_as_uint(f);
    return (b & 0x80000000u) ? ~b : (b | 0x80000000u);
}
__device__ __forceinline__ float ord2f(unsigned u) {
    return (u & 0x80000000u) ? __uint_as_float(u ^ 0x80000000u)
                             : __uint_as_float(~u);
}

// ---------------- GEMM: H[n,DOUT] = X[n,DIN] @ W[DIN,DOUT] ----------------
template <int DIN, int DOUT>
__global__ __launch_bounds__(256) void gemm_kernel(
    const float* __restrict__ X, const float* __restrict__ W,
    float* __restrict__ H, int n) {
    __shared__ float Ws[DIN * DOUT];
    // cooperative vectorized load of W into LDS
    const float4* W4 = reinterpret_cast<const float4*>(W);
    float4* Ws4 = reinterpret_cast<float4*>(Ws);
    for (int i = threadIdx.x; i < DIN * DOUT / 4; i += 256) Ws4[i] = W4[i];
    __syncthreads();

    constexpr int NPB = (256 / DOUT) > 0 ? (256 / DOUT) : 1;  // nodes per block
    const int j = threadIdx.x % DOUT;
    const int ln = threadIdx.x / DOUT;
    const int node = blockIdx.x * NPB + ln;
    if (node >= n) return;

    const float4* xrow = reinterpret_cast<const float4*>(X + (size_t)node * DIN);
    float acc = 0.f;
#pragma unroll 8
    for (int k4 = 0; k4 < DIN / 4; ++k4) {
        float4 x4 = xrow[k4];
        acc += x4.x * Ws[(4 * k4 + 0) * DOUT + j];
        acc += x4.y * Ws[(4 * k4 + 1) * DOUT + j];
        acc += x4.z * Ws[(4 * k4 + 2) * DOUT + j];
        acc += x4.w * Ws[(4 * k4 + 3) * DOUT + j];
    }
    H[(size_t)node * DOUT + j] = acc;
}

// ------------- per-node attention scores: s = H . a  (64 lanes/node) -------
__global__ __launch_bounds__(256) void scores_kernel(
    const float* __restrict__ H, const float* __restrict__ a_s,
    const float* __restrict__ a_d, float* __restrict__ s_src,
    float* __restrict__ s_dst, int n, int dout) {
    int t = blockIdx.x * 256 + threadIdx.x;
    int node = t >> 6;
    int lane = t & 63;
    if (node >= n) return;
    float ps = 0.f, pd = 0.f;
    for (int c = lane; c < dout; c += 64) {
        float h = H[(size_t)node * dout + c];
        ps += h * a_s[c];
        pd += h * a_d[c];
    }
#pragma unroll
    for (int off = 32; off; off >>= 1) {
        ps += __shfl_xor(ps, off);
        pd += __shfl_xor(pd, off);
    }
    if (lane == 0) {
        s_src[node] = ps;
        s_dst[node] = pd;
    }
}

// ------------- init: zero accumulator, m = -inf (ordered), denom = 0 -------
__global__ void init_kernel(float* __restrict__ acc, long acc_count,
                            unsigned* __restrict__ m_ord,
                            float* __restrict__ denom, int n) {
    long i = (long)blockIdx.x * blockDim.x + threadIdx.x;
    long stride = (long)gridDim.x * blockDim.x;
    for (long k = i; k < acc_count; k += stride) acc[k] = 0.f;
    for (long k = i; k < n; k += stride) {
        m_ord[k] = ORD_NEG_INF;
        denom[k] = 0.f;
    }
}

__device__ __forceinline__ void edge_sd(const int* __restrict__ src,
                                        const int* __restrict__ dst, int E,
                                        int e, int& s, int& d) {
    if (e < E) {
        s = src[e];
        d = dst[e];
    } else {
        s = e - E;
        d = s;
    }
}

// ------------- pass 1: segment max over dst --------------------------------
__global__ __launch_bounds__(256) void edge_max_kernel(
    const int* __restrict__ src, const int* __restrict__ dst, int E, int n,
    const float* __restrict__ s_src, const float* __restrict__ s_dst,
    unsigned* __restrict__ m_ord) {
    int tot = E + n;
    int stride = gridDim.x * blockDim.x;
    for (int e = blockIdx.x * blockDim.x + threadIdx.x; e < tot; e += stride) {
        int s, d;
        edge_sd(src, dst, E, e, s, d);
        float v = s_src[s] + s_dst[d];
        v = v >= 0.f ? v : SLOPE * v;
        atomicMax(&m_ord[d], f2ord(v));
    }
}

// ------------- pass 2: segment sum of exp(e - m) ---------------------------
__global__ __launch_bounds__(256) void edge_sum_kernel(
    const int* __restrict__ src, const int* __restrict__ dst, int E, int n,
    const float* __restrict__ s_src, const float* __restrict__ s_dst,
    const unsigned* __restrict__ m_ord, float* __restrict__ denom) {
    int tot = E + n;
    int stride = gridDim.x * blockDim.x;
    for (int e = blockIdx.x * blockDim.x + threadIdx.x; e < tot; e += stride) {
        int s, d;
        edge_sd(src, dst, E, e, s, d);
        float v = s_src[s] + s_dst[d];
        v = v >= 0.f ? v : SLOPE * v;
        float p = expf(v - ord2f(m_ord[d]));
        atomicAdd(&denom[d], p);
    }
}

// ------------- pass 3: out[dst] += alpha * h[src]  (one wave per edge) -----
__global__ __launch_bounds__(256) void edge_scatter_kernel(
    const int* __restrict__ src, const int* __restrict__ dst, int E, int n,
    const float* __restrict__ s_src, const float* __restrict__ s_dst,
    const unsigned* __restrict__ m_ord, const float* __restrict__ denom,
    const float* __restrict__ H, float* __restrict__ Acc, int dout) {
    int tot = E + n;
    int lane = threadIdx.x & 63;
    int wid = (blockIdx.x * 256 + threadIdx.x) >> 6;
    int nw = (gridDim.x * 256) >> 6;
    for (int e = wid; e < tot; e += nw) {
        int s, d;
        edge_sd(src, dst, E, e, s, d);
        float v = s_src[s] + s_dst[d];
        v = v >= 0.f ? v : SLOPE * v;
        float alpha = expf(v - ord2f(m_ord[d])) / (denom[d] + 1e-16f);
        const float* hrow = H + (size_t)s * dout;
        float* arow = Acc + (size_t)d * dout;
        for (int c = lane; c < dout; c += 64)
            atomicAdd(&arow[c], alpha * hrow[c]);
    }
}

// ------------- epilogue: x = BN(relu(acc + b)) (in place) ------------------
__global__ __launch_bounds__(256) void finalize_kernel(
    float* __restrict__ X, const float* __restrict__ bi,
    const float* __restrict__ g, const float* __restrict__ be, long count,
    int dmask, int bn) {
    long stride = (long)gridDim.x * blockDim.x;
    const float inv = rsqrtf(1.f + EPSV);
    for (long i = (long)blockIdx.x * blockDim.x + threadIdx.x; i < count;
         i += stride) {
        int j = (int)i & dmask;
        float v = X[i] + bi[j];
        v = fmaxf(v, 0.f);
        if (bn) v = v * (g[j] * inv) + be[j];
        X[i] = v;
    }
}

extern "C" void kernel_launch(void* const* d_in, const int* in_sizes, int n_in,
                              void* d_out, int out_size, void* d_ws,
                              size_t ws_size, hipStream_t stream) {
    const float* feat = (const float*)d_in[0];
    const int* eidx = (const int*)d_in[1];
    const float* W[4] = {(const float*)d_in[2], (const float*)d_in[6],
                         (const float*)d_in[10], (const float*)d_in[14]};
    const float* As[4] = {(const float*)d_in[3], (const float*)d_in[7],
                          (const float*)d_in[11], (const float*)d_in[15]};
    const float* Ad[4] = {(const float*)d_in[4], (const float*)d_in[8],
                          (const float*)d_in[12], (const float*)d_in[16]};
    const float* Bi[4] = {(const float*)d_in[5], (const float*)d_in[9],
                          (const float*)d_in[13], (const float*)d_in[17]};
    const float* G[3] = {(const float*)d_in[18], (const float*)d_in[20],
                         (const float*)d_in[22]};
    const float* Be[3] = {(const float*)d_in[19], (const float*)d_in[21],
                          (const float*)d_in[23]};

    const int N = in_sizes[0] / 256;
    const int E = in_sizes[1] / 2;
    const int tot = E + N;
    const int* srcA = eidx;
    const int* dstA = eidx + E;

    // workspace layout
    float* bufB = (float*)d_ws;                  // N*256  (h)
    float* bufA = bufB + (size_t)N * 256;        // N*64   (x / accumulator)
    float* s_src = bufA + (size_t)N * 64;        // N
    float* s_dst = s_src + N;                    // N
    unsigned* m_ord = (unsigned*)(s_dst + N);    // N
    float* denom = (float*)(m_ord + N);          // N
    float* outf = (float*)d_out;

    const int edge_grid = (tot + 255) / 256;
    const int scat_grid = 8192;
    const int score_grid = (N * 64 + 255) / 256;

    auto run_layer = [&](int li, const float* X, float* H, float* Acc, int din,
                         int dn, bool bn) {
        if (din == 256 && dn == 64)
            gemm_kernel<256, 64><<<(N + 3) / 4, 256, 0, stream>>>(X, W[li], H, N);
        else if (din == 64 && dn == 64)
            gemm_kernel<64, 64><<<(N + 3) / 4, 256, 0, stream>>>(X, W[li], H, N);
        else
            gemm_kernel<64, 256><<<N, 256, 0, stream>>>(X, W[li], H, N);

        scores_kernel<<<score_grid, 256, 0, stream>>>(H, As[li], Ad[li], s_src,
                                                      s_dst, N, dn);
        init_kernel<<<4096, 256, 0, stream>>>(Acc, (long)N * dn, m_ord, denom, N);
        edge_max_kernel<<<edge_grid, 256, 0, stream>>>(srcA, dstA, E, N, s_src,
                                                       s_dst, m_ord);
        edge_sum_kernel<<<edge_grid, 256, 0, stream>>>(srcA, dstA, E, N, s_src,
                                                       s_dst, m_ord, denom);
        edge_scatter_kernel<<<scat_grid, 256, 0, stream>>>(
            srcA, dstA, E, N, s_src, s_dst, m_ord, denom, H, Acc, dn);
        finalize_kernel<<<4096, 256, 0, stream>>>(
            Acc, Bi[li], bn ? G[li] : nullptr, bn ? Be[li] : nullptr,
            (long)N * dn, dn - 1, bn ? 1 : 0);
    };

    // encoder
    run_layer(0, feat, bufB, bufA, 256, 64, true);
    run_layer(1, bufA, bufB, bufA, 64, 64, true);
    // decoder
    run_layer(2, bufA, bufB, bufA, 64, 64, true);
    run_layer(3, bufA, bufB, outf, 64, 256, false);
}

// Round 2
// 2217.248 us; speedup vs baseline: 2.1844x; 2.1844x over previous
//
#include <hip/hip_runtime.h>
#include <cmath>

#define SLOPE 0.2f
#define EPSV 1e-5f

// ======================= CSR build (once per call) =======================
__global__ __launch_bounds__(256) void deg_init_kernel(int* __restrict__ deg, int n) {
    int i = blockIdx.x * 256 + threadIdx.x;
    if (i <= n) deg[i] = (i < n) ? 1 : 0;  // self-loop counts; virtual elem n = 0
}

__global__ __launch_bounds__(256) void hist_kernel(const int* __restrict__ dst, int E,
                                                   int* __restrict__ deg) {
    int stride = gridDim.x * 256;
    for (int e = blockIdx.x * 256 + threadIdx.x; e < E; e += stride)
        atomicAdd(&deg[dst[e]], 1);
}

__global__ __launch_bounds__(256) void scan_block_kernel(const int* __restrict__ deg,
                                                         int* __restrict__ row,
                                                         int* __restrict__ partials, int n1) {
    __shared__ int s[256];
    int t = threadIdx.x;
    int i = blockIdx.x * 256 + t;
    int v = (i < n1) ? deg[i] : 0;
    s[t] = v;
    __syncthreads();
    for (int off = 1; off < 256; off <<= 1) {
        int x = (t >= off) ? s[t - off] : 0;
        __syncthreads();
        s[t] += x;
        __syncthreads();
    }
    if (i < n1) row[i] = s[t] - v;  // exclusive (block-local)
    if (t == 255) partials[blockIdx.x] = s[255];
}

__global__ __launch_bounds__(1024) void scan_top_kernel(int* __restrict__ partials, int nb) {
    __shared__ int s[1024];
    int t = threadIdx.x;
    int v = (t < nb) ? partials[t] : 0;
    s[t] = v;
    __syncthreads();
    for (int off = 1; off < 1024; off <<= 1) {
        int x = (t >= off) ? s[t - off] : 0;
        __syncthreads();
        s[t] += x;
        __syncthreads();
    }
    if (t < nb) partials[t] = s[t] - v;  // exclusive block offsets
}

__global__ __launch_bounds__(256) void scan_add_kernel(int* __restrict__ row,
                                                       const int* __restrict__ partials, int n1) {
    int i = blockIdx.x * 256 + threadIdx.x;
    if (i < n1) row[i] += partials[blockIdx.x];
}

__global__ __launch_bounds__(256) void fill_self_kernel(const int* __restrict__ row,
                                                        int* __restrict__ cursor,
                                                        int* __restrict__ csr, int n) {
    int i = blockIdx.x * 256 + threadIdx.x;
    if (i < n) {
        int p = row[i];
        csr[p] = i;  // self-loop first
        cursor[i] = p + 1;
    }
}

__global__ __launch_bounds__(256) void fill_edge_kernel(const int* __restrict__ src,
                                                        const int* __restrict__ dst, int E,
                                                        int* __restrict__ cursor,
                                                        int* __restrict__ csr) {
    int stride = gridDim.x * 256;
    for (int e = blockIdx.x * 256 + threadIdx.x; e < E; e += stride) {
        int p = atomicAdd(&cursor[dst[e]], 1);
        csr[p] = src[e];
    }
}

// ============ GEMM h = X@W (DOUT=64) with fused attention scores ============
// block = 256 threads = 4 nodes x 64 lanes; lane == output channel.
template <int DIN>
__global__ __launch_bounds__(256) void gemm_scores_kernel(
    const float* __restrict__ X, const float* __restrict__ W,
    const float* __restrict__ a_s, const float* __restrict__ a_d,
    float* __restrict__ H, float* __restrict__ s_src, float* __restrict__ s_dst, int n) {
    __shared__ float Ws[DIN * 64];
    const float4* W4 = reinterpret_cast<const float4*>(W);
    float4* Ws4 = reinterpret_cast<float4*>(Ws);
    for (int i = threadIdx.x; i < DIN * 16; i += 256) Ws4[i] = W4[i];
    __syncthreads();

    const int lane = threadIdx.x & 63;
    const int node = blockIdx.x * 4 + (threadIdx.x >> 6);
    if (node >= n) return;

    const float4* xrow = reinterpret_cast<const float4*>(X + (size_t)node * DIN);
    float acc = 0.f;
#pragma unroll
    for (int k4 = 0; k4 < DIN / 4; ++k4) {
        float4 x4 = xrow[k4];
        acc = fmaf(x4.x, Ws[(4 * k4 + 0) * 64 + lane], acc);
        acc = fmaf(x4.y, Ws[(4 * k4 + 1) * 64 + lane], acc);
        acc = fmaf(x4.z, Ws[(4 * k4 + 2) * 64 + lane], acc);
        acc = fmaf(x4.w, Ws[(4 * k4 + 3) * 64 + lane], acc);
    }
    H[(size_t)node * 64 + lane] = acc;

    float ps = acc * a_s[lane];
    float pd = acc * a_d[lane];
#pragma unroll
    for (int off = 32; off; off >>= 1) {
        ps += __shfl_xor(ps, off);
        pd += __shfl_xor(pd, off);
    }
    if (lane == 0) {
        s_src[node] = ps;
        s_dst[node] = pd;
    }
}

// =========== scores directly from 64-dim x (layer 4, project-after) ==========
__global__ __launch_bounds__(256) void scores_x_kernel(
    const float* __restrict__ X, const float* __restrict__ Was,
    const float* __restrict__ Wad, float* __restrict__ s_src,
    float* __restrict__ s_dst, int n) {
    const int lane = threadIdx.x & 63;
    const int node = (blockIdx.x * 256 + threadIdx.x) >> 6;
    if (node >= n) return;
    float x = X[(size_t)node * 64 + lane];
    float ps = x * Was[lane];
    float pd = x * Wad[lane];
#pragma unroll
    for (int off = 32; off; off >>= 1) {
        ps += __shfl_xor(ps, off);
        pd += __shfl_xor(pd, off);
    }
    if (lane == 0) {
        s_src[node] = ps;
        s_dst[node] = pd;
    }
}

// ================== Wa = W @ a  (tiny, 1 block, 128 threads) =================
__global__ __launch_bounds__(128) void wa_kernel(const float* __restrict__ W /*64x256*/,
                                                 const float* __restrict__ a_s,
                                                 const float* __restrict__ a_d,
                                                 float* __restrict__ Was,
                                                 float* __restrict__ Wad) {
    int t = threadIdx.x;
    int k = t & 63;
    const float* a = (t < 64) ? a_s : a_d;
    float* o = (t < 64) ? Was : Wad;
    const float4* wr = reinterpret_cast<const float4*>(W + (size_t)k * 256);
    const float4* a4 = reinterpret_cast<const float4*>(a);
    float acc = 0.f;
#pragma unroll
    for (int j = 0; j < 64; ++j) {
        float4 w = wr[j];
        float4 av = a4[j];
        acc = fmaf(w.x, av.x, acc);
        acc = fmaf(w.y, av.y, acc);
        acc = fmaf(w.z, av.z, acc);
        acc = fmaf(w.w, av.w, acc);
    }
    o[k] = acc;
}

// ======== fused softmax + aggregate: one wave per dst node (dout=64) =========
// MODE 0: out = BN(relu(acc + bi));  MODE 1: out = acc (raw, for project-after)
template <int MODE>
__global__ __launch_bounds__(256) void gather_kernel(
    const int* __restrict__ row, const int* __restrict__ csr,
    const float* __restrict__ s_src, const float* __restrict__ s_dst,
    const float* __restrict__ H, const float* __restrict__ bi,
    const float* __restrict__ g, const float* __restrict__ be,
    float* __restrict__ Out, int n) {
    const int lane = threadIdx.x & 63;
    const int node = (blockIdx.x * 256 + threadIdx.x) >> 6;
    if (node >= n) return;
    const int beg = row[node];
    const int end = row[node + 1];
    const float sdd = s_dst[node];

    // pass 1a: max over edges (lane-parallel)
    float m = -1e30f;
    for (int e = beg + lane; e < end; e += 64) {
        float v = s_src[csr[e]] + sdd;
        v = v >= 0.f ? v : SLOPE * v;
        m = fmaxf(m, v);
    }
#pragma unroll
    for (int off = 32; off; off >>= 1) m = fmaxf(m, __shfl_xor(m, off));

    // pass 1b: denom
    float dl = 0.f;
    for (int e = beg + lane; e < end; e += 64) {
        float v = s_src[csr[e]] + sdd;
        v = v >= 0.f ? v : SLOPE * v;
        dl += __expf(v - m);
    }
#pragma unroll
    for (int off = 32; off; off >>= 1) dl += __shfl_xor(dl, off);
    const float invden = 1.f / (dl + 1e-16f);

    // pass 2: weighted accumulation, lane = channel
    float acc = 0.f;
    for (int e = beg; e < end; ++e) {
        int s = csr[e];
        float v = s_src[s] + sdd;
        v = v >= 0.f ? v : SLOPE * v;
        float al = __expf(v - m) * invden;
        acc = fmaf(al, H[(size_t)s * 64 + lane], acc);
    }

    float o;
    if (MODE == 0) {
        o = fmaxf(acc + bi[lane], 0.f) * (g[lane] * rsqrtf(1.f + EPSV)) + be[lane];
    } else {
        o = acc;
    }
    Out[(size_t)node * 64 + lane] = o;
}

// ========= layer-4 projection: Out = relu(Agg @ W + b), 64 -> 256 ===========
__global__ __launch_bounds__(256) void gemm_out_kernel(const float* __restrict__ X,
                                                       const float* __restrict__ W,
                                                       const float* __restrict__ bi,
                                                       float* __restrict__ Out, int n) {
    __shared__ float Ws[64 * 256];
    const float4* W4 = reinterpret_cast<const float4*>(W);
    float4* Ws4 = reinterpret_cast<float4*>(Ws);
    for (int i = threadIdx.x; i < 64 * 64; i += 256) Ws4[i] = W4[i];
    __syncthreads();

    const int j = threadIdx.x;
    const int node = blockIdx.x;
    if (node >= n) return;
    const float4* xrow = reinterpret_cast<const float4*>(X + (size_t)node * 64);
    float acc = 0.f;
#pragma unroll
    for (int k4 = 0; k4 < 16; ++k4) {
        float4 x4 = xrow[k4];
        acc = fmaf(x4.x, Ws[(4 * k4 + 0) * 256 + j], acc);
        acc = fmaf(x4.y, Ws[(4 * k4 + 1) * 256 + j], acc);
        acc = fmaf(x4.z, Ws[(4 * k4 + 2) * 256 + j], acc);
        acc = fmaf(x4.w, Ws[(4 * k4 + 3) * 256 + j], acc);
    }
    Out[(size_t)node * 256 + j] = fmaxf(acc + bi[j], 0.f);
}

// ================================ launcher ===================================
extern "C" void kernel_launch(void* const* d_in, const int* in_sizes, int n_in,
                              void* d_out, int out_size, void* d_ws,
                              size_t ws_size, hipStream_t stream) {
    const float* feat = (const float*)d_in[0];
    const int* eidx = (const int*)d_in[1];
    const float* W[4] = {(const float*)d_in[2], (const float*)d_in[6],
                         (const float*)d_in[10], (const float*)d_in[14]};
    const float* As[4] = {(const float*)d_in[3], (const float*)d_in[7],
                          (const float*)d_in[11], (const float*)d_in[15]};
    const float* Ad[4] = {(const float*)d_in[4], (const float*)d_in[8],
                          (const float*)d_in[12], (const float*)d_in[16]};
    const float* Bi[4] = {(const float*)d_in[5], (const float*)d_in[9],
                          (const float*)d_in[13], (const float*)d_in[17]};
    const float* G[3] = {(const float*)d_in[18], (const float*)d_in[20],
                         (const float*)d_in[22]};
    const float* Be[3] = {(const float*)d_in[19], (const float*)d_in[21],
                          (const float*)d_in[23]};

    const int N = in_sizes[0] / 256;
    const int E = in_sizes[1] / 2;
    const int* srcA = eidx;
    const int* dstA = eidx + E;

    // ---------------- workspace layout (floats unless noted) ----------------
    float* h = (float*)d_ws;                       // N*64  (h, also layer-4 Agg)
    float* xA = h + (size_t)N * 64;                // N*64
    float* xB = xA + (size_t)N * 64;               // N*64
    float* s_src = xB + (size_t)N * 64;            // N
    float* s_dst = s_src + N;                      // N
    float* Was = s_dst + N;                        // 64
    float* Wad = Was + 64;                         // 64
    int* deg = (int*)(Wad + 64);                   // N+1
    int* row = deg + (N + 1);                      // N+1
    int* cursor = row + (N + 1);                   // N
    int* partials = cursor + N;                    // 1024
    int* csr = partials + 1024;                    // E+N

    const int n1 = N + 1;
    const int NB1 = (n1 + 255) / 256;
    const int node_grid = (N + 3) / 4;             // 4 nodes (waves) per block
    const int edge_grid = (E + 255) / 256;

    // ---------------- build CSR (once; reused by all 4 layers) --------------
    deg_init_kernel<<<NB1, 256, 0, stream>>>(deg, N);
    hist_kernel<<<2048, 256, 0, stream>>>(dstA, E, deg);
    scan_block_kernel<<<NB1, 256, 0, stream>>>(deg, row, partials, n1);
    scan_top_kernel<<<1, 1024, 0, stream>>>(partials, NB1);
    scan_add_kernel<<<NB1, 256, 0, stream>>>(row, partials, n1);
    fill_self_kernel<<<NB1, 256, 0, stream>>>(row, cursor, csr, N);
    fill_edge_kernel<<<2048, 256, 0, stream>>>(srcA, dstA, E, cursor, csr);

    // ---------------- layer 1: 256 -> 64, BN -------------------------------
    gemm_scores_kernel<256><<<node_grid, 256, 0, stream>>>(
        feat, W[0], As[0], Ad[0], h, s_src, s_dst, N);
    gather_kernel<0><<<node_grid, 256, 0, stream>>>(
        row, csr, s_src, s_dst, h, Bi[0], G[0], Be[0], xA, N);

    // ---------------- layer 2: 64 -> 64, BN --------------------------------
    gemm_scores_kernel<64><<<node_grid, 256, 0, stream>>>(
        xA, W[1], As[1], Ad[1], h, s_src, s_dst, N);
    gather_kernel<0><<<node_grid, 256, 0, stream>>>(
        row, csr, s_src, s_dst, h, Bi[1], G[1], Be[1], xB, N);

    // ---------------- layer 3: 64 -> 64, BN --------------------------------
    gemm_scores_kernel<64><<<node_grid, 256, 0, stream>>>(
        xB, W[2], As[2], Ad[2], h, s_src, s_dst, N);
    gather_kernel<0><<<node_grid, 256, 0, stream>>>(
        row, csr, s_src, s_dst, h, Bi[2], G[2], Be[2], xA, N);

    // ---------------- layer 4: aggregate in 64-dim, project after ----------
    wa_kernel<<<1, 128, 0, stream>>>(W[3], As[3], Ad[3], Was, Wad);
    scores_x_kernel<<<node_grid, 256, 0, stream>>>(xA, Was, Wad, s_src, s_dst, N);
    gather_kernel<1><<<node_grid, 256, 0, stream>>>(
        row, csr, s_src, s_dst, xA, nullptr, nullptr, nullptr, h, N);
    gemm_out_kernel<<<N, 256, 0, stream>>>(h, W[3], Bi[3], (float*)d_out, N);
}

// Round 3
// 1107.820 us; speedup vs baseline: 4.3719x; 2.0015x over previous
//
#include <hip/hip_runtime.h>
#include <cmath>

#define SLOPE 0.2f
#define EPSV 1e-5f

// ======================= CSR build (once per call) =======================
__global__ __launch_bounds__(256) void deg_init_kernel(int* __restrict__ deg, int n) {
    int i = blockIdx.x * 256 + threadIdx.x;
    if (i <= n) deg[i] = (i < n) ? 1 : 0;  // self-loop counts; virtual elem n = 0
}

__global__ __launch_bounds__(256) void hist_kernel(const int* __restrict__ dst, int E,
                                                   int* __restrict__ deg) {
    int stride = gridDim.x * 256;
    for (int e = blockIdx.x * 256 + threadIdx.x; e < E; e += stride)
        atomicAdd(&deg[dst[e]], 1);
}

__global__ __launch_bounds__(256) void scan_block_kernel(const int* __restrict__ deg,
                                                         int* __restrict__ row,
                                                         int* __restrict__ partials, int n1) {
    __shared__ int s[256];
    int t = threadIdx.x;
    int i = blockIdx.x * 256 + t;
    int v = (i < n1) ? deg[i] : 0;
    s[t] = v;
    __syncthreads();
    for (int off = 1; off < 256; off <<= 1) {
        int x = (t >= off) ? s[t - off] : 0;
        __syncthreads();
        s[t] += x;
        __syncthreads();
    }
    if (i < n1) row[i] = s[t] - v;  // exclusive (block-local)
    if (t == 255) partials[blockIdx.x] = s[255];
}

__global__ __launch_bounds__(1024) void scan_top_kernel(int* __restrict__ partials, int nb) {
    __shared__ int s[1024];
    int t = threadIdx.x;
    int v = (t < nb) ? partials[t] : 0;
    s[t] = v;
    __syncthreads();
    for (int off = 1; off < 1024; off <<= 1) {
        int x = (t >= off) ? s[t - off] : 0;
        __syncthreads();
        s[t] += x;
        __syncthreads();
    }
    if (t < nb) partials[t] = s[t] - v;  // exclusive block offsets
}

__global__ __launch_bounds__(256) void scan_add_kernel(int* __restrict__ row,
                                                       const int* __restrict__ partials, int n1) {
    int i = blockIdx.x * 256 + threadIdx.x;
    if (i < n1) row[i] += partials[blockIdx.x];
}

__global__ __launch_bounds__(256) void fill_self_kernel(const int* __restrict__ row,
                                                        int* __restrict__ cursor,
                                                        int* __restrict__ csr, int n) {
    int i = blockIdx.x * 256 + threadIdx.x;
    if (i < n) {
        int p = row[i];
        csr[p] = i;  // self-loop first
        cursor[i] = p + 1;
    }
}

__global__ __launch_bounds__(256) void fill_edge_kernel(const int* __restrict__ src,
                                                        const int* __restrict__ dst, int E,
                                                        int* __restrict__ cursor,
                                                        int* __restrict__ csr) {
    int stride = gridDim.x * 256;
    for (int e = blockIdx.x * 256 + threadIdx.x; e < E; e += stride) {
        int p = atomicAdd(&cursor[dst[e]], 1);
        csr[p] = src[e];
    }
}

// ============ GEMM h = X@W (DOUT=64) with fused attention scores ============
// Persistent blocks: W staged to LDS ONCE per block. 4 waves/block; each wave
// processes 4 nodes at a time so each LDS read of W feeds 4 FMAs.
template <int DIN>
__device__ __forceinline__ float dot1(const float* __restrict__ Ws,
                                      const float* __restrict__ X, int node, int lane) {
    const float4* xr = reinterpret_cast<const float4*>(X + (size_t)node * DIN);
    float acc = 0.f;
#pragma unroll 8
    for (int k4 = 0; k4 < DIN / 4; ++k4) {
        float4 x4 = xr[k4];
        acc = fmaf(x4.x, Ws[(4 * k4 + 0) * 64 + lane], acc);
        acc = fmaf(x4.y, Ws[(4 * k4 + 1) * 64 + lane], acc);
        acc = fmaf(x4.z, Ws[(4 * k4 + 2) * 64 + lane], acc);
        acc = fmaf(x4.w, Ws[(4 * k4 + 3) * 64 + lane], acc);
    }
    return acc;
}

template <int DIN>
__global__ __launch_bounds__(256) void gemm_scores_kernel(
    const float* __restrict__ X, const float* __restrict__ W,
    const float* __restrict__ a_s, const float* __restrict__ a_d,
    float* __restrict__ H, float* __restrict__ s_src, float* __restrict__ s_dst, int n) {
    __shared__ float Ws[DIN * 64];
    const float4* W4 = reinterpret_cast<const float4*>(W);
    float4* Ws4 = reinterpret_cast<float4*>(Ws);
    for (int i = threadIdx.x; i < DIN * 16; i += 256) Ws4[i] = W4[i];
    __syncthreads();

    const int lane = threadIdx.x & 63;
    const int wv = threadIdx.x >> 6;
    const float as_l = a_s[lane];
    const float ad_l = a_d[lane];
    const int stride = gridDim.x * 16;

    for (int base = (blockIdx.x * 4 + wv) * 4; base < n; base += stride) {
        if (base + 4 <= n) {
            const float4* x0 = reinterpret_cast<const float4*>(X + (size_t)(base + 0) * DIN);
            const float4* x1 = reinterpret_cast<const float4*>(X + (size_t)(base + 1) * DIN);
            const float4* x2 = reinterpret_cast<const float4*>(X + (size_t)(base + 2) * DIN);
            const float4* x3 = reinterpret_cast<const float4*>(X + (size_t)(base + 3) * DIN);
            float acc0 = 0.f, acc1 = 0.f, acc2 = 0.f, acc3 = 0.f;
#pragma unroll 8
            for (int k4 = 0; k4 < DIN / 4; ++k4) {
                float4 a = x0[k4], b = x1[k4], c = x2[k4], d = x3[k4];
                float w0 = Ws[(4 * k4 + 0) * 64 + lane];
                float w1 = Ws[(4 * k4 + 1) * 64 + lane];
                float w2 = Ws[(4 * k4 + 2) * 64 + lane];
                float w3 = Ws[(4 * k4 + 3) * 64 + lane];
                acc0 = fmaf(a.x, w0, fmaf(a.y, w1, fmaf(a.z, w2, fmaf(a.w, w3, acc0))));
                acc1 = fmaf(b.x, w0, fmaf(b.y, w1, fmaf(b.z, w2, fmaf(b.w, w3, acc1))));
                acc2 = fmaf(c.x, w0, fmaf(c.y, w1, fmaf(c.z, w2, fmaf(c.w, w3, acc2))));
                acc3 = fmaf(d.x, w0, fmaf(d.y, w1, fmaf(d.z, w2, fmaf(d.w, w3, acc3))));
            }
            H[(size_t)(base + 0) * 64 + lane] = acc0;
            H[(size_t)(base + 1) * 64 + lane] = acc1;
            H[(size_t)(base + 2) * 64 + lane] = acc2;
            H[(size_t)(base + 3) * 64 + lane] = acc3;
            float p0s = acc0 * as_l, p0d = acc0 * ad_l;
            float p1s = acc1 * as_l, p1d = acc1 * ad_l;
            float p2s = acc2 * as_l, p2d = acc2 * ad_l;
            float p3s = acc3 * as_l, p3d = acc3 * ad_l;
#pragma unroll
            for (int off = 32; off; off >>= 1) {
                p0s += __shfl_xor(p0s, off); p0d += __shfl_xor(p0d, off);
                p1s += __shfl_xor(p1s, off); p1d += __shfl_xor(p1d, off);
                p2s += __shfl_xor(p2s, off); p2d += __shfl_xor(p2d, off);
                p3s += __shfl_xor(p3s, off); p3d += __shfl_xor(p3d, off);
            }
            if (lane == 0) {
                s_src[base + 0] = p0s; s_dst[base + 0] = p0d;
                s_src[base + 1] = p1s; s_dst[base + 1] = p1d;
                s_src[base + 2] = p2s; s_dst[base + 2] = p2d;
                s_src[base + 3] = p3s; s_dst[base + 3] = p3d;
            }
        } else {
            for (int node = base; node < n; ++node) {
                float acc = dot1<DIN>(Ws, X, node, lane);
                H[(size_t)node * 64 + lane] = acc;
                float ps = acc * as_l, pd = acc * ad_l;
#pragma unroll
                for (int off = 32; off; off >>= 1) {
                    ps += __shfl_xor(ps, off);
                    pd += __shfl_xor(pd, off);
                }
                if (lane == 0) { s_src[node] = ps; s_dst[node] = pd; }
            }
        }
    }
}

// =========== scores directly from 64-dim x (layer 4, project-after) ==========
__global__ __launch_bounds__(256) void scores_x_kernel(
    const float* __restrict__ X, const float* __restrict__ Was,
    const float* __restrict__ Wad, float* __restrict__ s_src,
    float* __restrict__ s_dst, int n) {
    const int lane = threadIdx.x & 63;
    const int node = (blockIdx.x * 256 + threadIdx.x) >> 6;
    if (node >= n) return;
    float x = X[(size_t)node * 64 + lane];
    float ps = x * Was[lane];
    float pd = x * Wad[lane];
#pragma unroll
    for (int off = 32; off; off >>= 1) {
        ps += __shfl_xor(ps, off);
        pd += __shfl_xor(pd, off);
    }
    if (lane == 0) {
        s_src[node] = ps;
        s_dst[node] = pd;
    }
}

// ================== Wa = W @ a  (tiny, 1 block, 128 threads) =================
__global__ __launch_bounds__(128) void wa_kernel(const float* __restrict__ W /*64x256*/,
                                                 const float* __restrict__ a_s,
                                                 const float* __restrict__ a_d,
                                                 float* __restrict__ Was,
                                                 float* __restrict__ Wad) {
    int t = threadIdx.x;
    int k = t & 63;
    const float* a = (t < 64) ? a_s : a_d;
    float* o = (t < 64) ? Was : Wad;
    const float4* wr = reinterpret_cast<const float4*>(W + (size_t)k * 256);
    const float4* a4 = reinterpret_cast<const float4*>(a);
    float acc = 0.f;
#pragma unroll
    for (int j = 0; j < 64; ++j) {
        float4 w = wr[j];
        float4 av = a4[j];
        acc = fmaf(w.x, av.x, acc);
        acc = fmaf(w.y, av.y, acc);
        acc = fmaf(w.z, av.z, acc);
        acc = fmaf(w.w, av.w, acc);
    }
    o[k] = acc;
}

// ======== fused softmax + aggregate: one wave per dst node (dout=64) =========
// Online max+sum in ONE lane-parallel pass; first-64-edge src/prob cached in
// registers and redistributed via shuffles; 8-deep ILP on H-row gathers.
// MODE 0: out = BN(relu(acc + bi));  MODE 1: out = acc (raw, for project-after)
template <int MODE>
__global__ __launch_bounds__(256) void gather_kernel(
    const int* __restrict__ row, const int* __restrict__ csr,
    const float* __restrict__ s_src, const float* __restrict__ s_dst,
    const float* __restrict__ H, const float* __restrict__ bi,
    const float* __restrict__ g, const float* __restrict__ be,
    float* __restrict__ Out, int n) {
    const int lane = threadIdx.x & 63;
    const int node = (blockIdx.x * 256 + threadIdx.x) >> 6;
    if (node >= n) return;
    const int beg = row[node];
    const int end = row[node + 1];
    const int deg = end - beg;
    const float sdd = s_dst[node];

    // --- pass 1: online max+denominator (lane-parallel), cache first 64 ---
    const int e0 = beg + lane;
    int c0 = 0;
    float v0 = -1e30f;
    bool has0 = (e0 < end);
    if (has0) {
        c0 = csr[e0];
        float t = s_src[c0] + sdd;
        v0 = t >= 0.f ? t : SLOPE * t;
    }
    float m = v0;
    float dl = has0 ? 1.f : 0.f;
    for (int e = e0 + 64; e < end; e += 64) {
        int s = csr[e];
        float t = s_src[s] + sdd;
        t = t >= 0.f ? t : SLOPE * t;
        float nm = fmaxf(m, t);
        dl = dl * __expf(m - nm) + __expf(t - nm);
        m = nm;
    }
    float M = m;
#pragma unroll
    for (int off = 32; off; off >>= 1) M = fmaxf(M, __shfl_xor(M, off));
    dl *= __expf(m - M);
#pragma unroll
    for (int off = 32; off; off >>= 1) dl += __shfl_xor(dl, off);
    const float invden = 1.f / (dl + 1e-16f);
    const float p0 = has0 ? __expf(v0 - M) : 0.f;

    // --- pass 2: weighted accumulation, lane = channel ---
    float acc = 0.f;
    const int nf = deg < 64 ? deg : 64;
    int k = 0;
    for (; k + 8 <= nf; k += 8) {
        int s0 = __shfl(c0, k + 0), s1 = __shfl(c0, k + 1);
        int s2 = __shfl(c0, k + 2), s3 = __shfl(c0, k + 3);
        int s4 = __shfl(c0, k + 4), s5 = __shfl(c0, k + 5);
        int s6 = __shfl(c0, k + 6), s7 = __shfl(c0, k + 7);
        float a0 = __shfl(p0, k + 0), a1 = __shfl(p0, k + 1);
        float a2 = __shfl(p0, k + 2), a3 = __shfl(p0, k + 3);
        float a4 = __shfl(p0, k + 4), a5 = __shfl(p0, k + 5);
        float a6 = __shfl(p0, k + 6), a7 = __shfl(p0, k + 7);
        float h0 = H[(size_t)s0 * 64 + lane], h1 = H[(size_t)s1 * 64 + lane];
        float h2 = H[(size_t)s2 * 64 + lane], h3 = H[(size_t)s3 * 64 + lane];
        float h4 = H[(size_t)s4 * 64 + lane], h5 = H[(size_t)s5 * 64 + lane];
        float h6 = H[(size_t)s6 * 64 + lane], h7 = H[(size_t)s7 * 64 + lane];
        acc = fmaf(a0, h0, acc); acc = fmaf(a1, h1, acc);
        acc = fmaf(a2, h2, acc); acc = fmaf(a3, h3, acc);
        acc = fmaf(a4, h4, acc); acc = fmaf(a5, h5, acc);
        acc = fmaf(a6, h6, acc); acc = fmaf(a7, h7, acc);
    }
    for (; k < nf; ++k) {
        int s = __shfl(c0, k);
        float a = __shfl(p0, k);
        acc = fmaf(a, H[(size_t)s * 64 + lane], acc);
    }
    for (int e = beg + 64; e < end; ++e) {  // rare overflow (deg > 64)
        int s = csr[e];
        float t = s_src[s] + sdd;
        t = t >= 0.f ? t : SLOPE * t;
        acc = fmaf(__expf(t - M), H[(size_t)s * 64 + lane], acc);
    }
    acc *= invden;

    float o;
    if (MODE == 0) {
        o = fmaxf(acc + bi[lane], 0.f) * (g[lane] * rsqrtf(1.f + EPSV)) + be[lane];
    } else {
        o = acc;
    }
    Out[(size_t)node * 64 + lane] = o;
}

// ========= layer-4 projection: Out = relu(Agg @ W + b), 64 -> 256 ===========
// Persistent blocks; thread j holds W[:,j] in 64 registers (static indices).
__global__ __launch_bounds__(256) void gemm_out_kernel(const float* __restrict__ X,
                                                       const float* __restrict__ W,
                                                       const float* __restrict__ bi,
                                                       float* __restrict__ Out, int n) {
    const int j = threadIdx.x;
    float wcol[64];
#pragma unroll
    for (int k = 0; k < 64; ++k) wcol[k] = W[k * 256 + j];
    const float bj = bi[j];
    for (int node = blockIdx.x; node < n; node += gridDim.x) {
        const float4* xr = reinterpret_cast<const float4*>(X + (size_t)node * 64);
        float acc = 0.f;
#pragma unroll
        for (int k4 = 0; k4 < 16; ++k4) {
            float4 x4 = xr[k4];
            acc = fmaf(x4.x, wcol[4 * k4 + 0],
                  fmaf(x4.y, wcol[4 * k4 + 1],
                  fmaf(x4.z, wcol[4 * k4 + 2],
                  fmaf(x4.w, wcol[4 * k4 + 3], acc))));
        }
        Out[(size_t)node * 256 + j] = fmaxf(acc + bj, 0.f);
    }
}

// ================================ launcher ===================================
extern "C" void kernel_launch(void* const* d_in, const int* in_sizes, int n_in,
                              void* d_out, int out_size, void* d_ws,
                              size_t ws_size, hipStream_t stream) {
    const float* feat = (const float*)d_in[0];
    const int* eidx = (const int*)d_in[1];
    const float* W[4] = {(const float*)d_in[2], (const float*)d_in[6],
                         (const float*)d_in[10], (const float*)d_in[14]};
    const float* As[4] = {(const float*)d_in[3], (const float*)d_in[7],
                          (const float*)d_in[11], (const float*)d_in[15]};
    const float* Ad[4] = {(const float*)d_in[4], (const float*)d_in[8],
                          (const float*)d_in[12], (const float*)d_in[16]};
    const float* Bi[4] = {(const float*)d_in[5], (const float*)d_in[9],
                          (const float*)d_in[13], (const float*)d_in[17]};
    const float* G[3] = {(const float*)d_in[18], (const float*)d_in[20],
                         (const float*)d_in[22]};
    const float* Be[3] = {(const float*)d_in[19], (const float*)d_in[21],
                          (const float*)d_in[23]};

    const int N = in_sizes[0] / 256;
    const int E = in_sizes[1] / 2;
    const int* srcA = eidx;
    const int* dstA = eidx + E;

    // ---------------- workspace layout (floats unless noted) ----------------
    float* h = (float*)d_ws;                       // N*64  (h, also layer-4 Agg)
    float* xA = h + (size_t)N * 64;                // N*64
    float* xB = xA + (size_t)N * 64;               // N*64
    float* s_src = xB + (size_t)N * 64;            // N
    float* s_dst = s_src + N;                      // N
    float* Was = s_dst + N;                        // 64
    float* Wad = Was + 64;                         // 64
    int* deg = (int*)(Wad + 64);                   // N+1
    int* row = deg + (N + 1);                      // N+1
    int* cursor = row + (N + 1);                   // N
    int* partials = cursor + N;                    // 1024
    int* csr = partials + 1024;                    // E+N

    const int n1 = N + 1;
    const int NB1 = (n1 + 255) / 256;
    const int node_grid = (N + 3) / 4;             // one wave per node
    (void)ws_size; (void)n_in; (void)out_size;

    // ---------------- build CSR (once; reused by all 4 layers) --------------
    deg_init_kernel<<<NB1, 256, 0, stream>>>(deg, N);
    hist_kernel<<<2048, 256, 0, stream>>>(dstA, E, deg);
    scan_block_kernel<<<NB1, 256, 0, stream>>>(deg, row, partials, n1);
    scan_top_kernel<<<1, 1024, 0, stream>>>(partials, NB1);
    scan_add_kernel<<<NB1, 256, 0, stream>>>(row, partials, n1);
    fill_self_kernel<<<NB1, 256, 0, stream>>>(row, cursor, csr, N);
    fill_edge_kernel<<<2048, 256, 0, stream>>>(srcA, dstA, E, cursor, csr);

    // ---------------- layer 1: 256 -> 64, BN -------------------------------
    gemm_scores_kernel<256><<<512, 256, 0, stream>>>(
        feat, W[0], As[0], Ad[0], h, s_src, s_dst, N);
    gather_kernel<0><<<node_grid, 256, 0, stream>>>(
        row, csr, s_src, s_dst, h, Bi[0], G[0], Be[0], xA, N);

    // ---------------- layer 2: 64 -> 64, BN --------------------------------
    gemm_scores_kernel<64><<<1024, 256, 0, stream>>>(
        xA, W[1], As[1], Ad[1], h, s_src, s_dst, N);
    gather_kernel<0><<<node_grid, 256, 0, stream>>>(
        row, csr, s_src, s_dst, h, Bi[1], G[1], Be[1], xB, N);

    // ---------------- layer 3: 64 -> 64, BN --------------------------------
    gemm_scores_kernel<64><<<1024, 256, 0, stream>>>(
        xB, W[2], As[2], Ad[2], h, s_src, s_dst, N);
    gather_kernel<0><<<node_grid, 256, 0, stream>>>(
        row, csr, s_src, s_dst, h, Bi[2], G[2], Be[2], xA, N);

    // ---------------- layer 4: aggregate in 64-dim, project after ----------
    wa_kernel<<<1, 128, 0, stream>>>(W[3], As[3], Ad[3], Was, Wad);
    scores_x_kernel<<<node_grid, 256, 0, stream>>>(xA, Was, Wad, s_src, s_dst, N);
    gather_kernel<1><<<node_grid, 256, 0, stream>>>(
        row, csr, s_src, s_dst, xA, nullptr, nullptr, nullptr, h, N);
    gemm_out_kernel<<<2048, 256, 0, stream>>>(h, W[3], Bi[3], (float*)d_out, N);
}